// Round 1
// baseline (66.379 us; speedup 1.0000x reference)
//
#include <hip/hip_runtime.h>
#include <stdint.h>

#define IN_   128
#define OUT_  128
#define BATCH_ 128
#define KK_   16
#define BPB   32                      // batches per block
// grid = OUT_ * (BATCH_/BPB) = 512 blocks, 256 threads

__global__ __launch_bounds__(256) void linlut_kernel(
    const float* __restrict__ x, const float* __restrict__ w,
    const float* __restrict__ bias, const float* __restrict__ means,
    const int* __restrict__ mask, float* __restrict__ out)
{
    __shared__ float    lut[128 * 33];   // lut[i*33 + lvl*16 + S], row padded to 33
    __shared__ uint32_t sbw[BPB * 33];   // packed sign bytes, row stride 33 words (132B)
    __shared__ uint32_t pidx[128];       // 4 gather indices per i, byte-packed

    const int tid = threadIdx.x;
    const int o  = blockIdx.x >> 2;
    const int b0 = (blockIdx.x & 3) * BPB;

    const float m0 = fabsf(means[0]);
    const float m1 = fabsf(means[1]);

    // ---- stage 1: pack gather indices for this o ----
    if (tid < 128) {
        const int4 mm = *(const int4*)(mask + ((size_t)(o * IN_ + tid)) * 4);
        pidx[tid] = (uint32_t)mm.x | ((uint32_t)mm.y << 8) |
                    ((uint32_t)mm.z << 16) | ((uint32_t)mm.w << 24);
    }

    // ---- stage 2: sign bytes (s0 | s1<<1) for our 32 batches ----
    #pragma unroll
    for (int r = 0; r < 4; ++r) {
        const int item = tid + 256 * r;      // 0..1023
        const int b    = item >> 5;          // 0..31 local batch
        const int g    = item & 31;          // group of 4 consecutive i
        const float4 xv = *(const float4*)(x + (size_t)(b0 + b) * IN_ + g * 4);
        float vv[4] = {xv.x, xv.y, xv.z, xv.w};
        uint32_t wd = 0;
        #pragma unroll
        for (int k = 0; k < 4; ++k) {
            const uint32_t s0 = (vv[k] >= 0.0f) ? 1u : 0u;
            const float rr = vv[k] - (s0 ? m0 : -m0);   // exact same f32 ops as reference
            const uint32_t s1 = (rr >= 0.0f) ? 1u : 0u;
            wd |= (s0 | (s1 << 1)) << (8 * k);
        }
        sbw[b * 33 + g] = wd;
    }

    // ---- stage 3: LUT slice for this o: lut[i][lvl*16+S] ----
    {
        const int i   = tid >> 1;        // 0..127
        const int lvl = tid & 1;
        const float m = lvl ? m1 : m0;
        const float p = (1.0f + m) * 0.5f;
        const float q = (1.0f - m) * 0.5f;
        float pw[5];
        pw[0] = p * p * p * p;
        pw[1] = p * p * p * q;
        pw[2] = p * p * q * q;
        pw[3] = p * q * q * q;
        pw[4] = q * q * q * q;
        const float* wr = w + ((size_t)(o * IN_ + i)) * KK_;
        float wv[16];
        #pragma unroll
        for (int c4 = 0; c4 < 4; ++c4) {
            const float4 t = *(const float4*)(wr + 4 * c4);
            wv[4 * c4 + 0] = t.x; wv[4 * c4 + 1] = t.y;
            wv[4 * c4 + 2] = t.z; wv[4 * c4 + 3] = t.w;
        }
        float* lr = lut + i * 33 + lvl * 16;
        #pragma unroll
        for (int S = 0; S < 16; ++S) {
            float acc = 0.0f;
            #pragma unroll
            for (int c = 0; c < 16; ++c)
                acc += wv[c] * pw[__popc(S ^ c)];   // popc folds at compile time
            lr[S] = acc;
        }
    }
    __syncthreads();

    // ---- stage 4: main loop — 8 threads per batch, 16 i's each ----
    const int part = tid & 7;
    const int bloc = tid >> 3;           // 0..31
    const unsigned char* sbb = ((const unsigned char*)sbw) + bloc * 132;
    float acc = 0.0f;
    #pragma unroll
    for (int j = 0; j < 16; ++j) {
        const int i = part + 8 * j;
        const uint32_t pk = pidx[i];
        const uint32_t c0 = sbb[pk & 255u];
        const uint32_t c1 = sbb[(pk >> 8) & 255u];
        const uint32_t c2 = sbb[(pk >> 16) & 255u];
        const uint32_t c3 = sbb[pk >> 24];
        const uint32_t S0 = (c0 & 1u) | ((c1 & 1u) << 1) | ((c2 & 1u) << 2) | ((c3 & 1u) << 3);
        const uint32_t S1 = (c0 >> 1) | ((c1 >> 1) << 1) | ((c2 >> 1) << 2) | ((c3 >> 1) << 3);
        const float* lr = lut + i * 33;
        acc += lr[S0];
        acc += lr[16 + S1];
    }
    acc += __shfl_xor(acc, 1);
    acc += __shfl_xor(acc, 2);
    acc += __shfl_xor(acc, 4);
    if (part == 0) {
        const int b = b0 + bloc;
        out[(size_t)b * OUT_ + o] = acc + bias[o];
    }
}

extern "C" void kernel_launch(void* const* d_in, const int* in_sizes, int n_in,
                              void* d_out, int out_size, void* d_ws, size_t ws_size,
                              hipStream_t stream) {
    const float* x     = (const float*)d_in[0];
    const float* w     = (const float*)d_in[1];
    const float* bias  = (const float*)d_in[2];
    const float* means = (const float*)d_in[3];
    const int*   mask  = (const int*)d_in[4];
    float* out = (float*)d_out;
    hipLaunchKernelGGL(linlut_kernel, dim3(512), dim3(256), 0, stream,
                       x, w, bias, means, mask, out);
}

// Round 2
// 65.909 us; speedup vs baseline: 1.0071x; 1.0071x over previous
//
#include <hip/hip_runtime.h>
#include <stdint.h>

#define IN_    128
#define OUT_   128
#define BATCH_ 128
#define KK_    16
#define BPB    32                     // batches per block
#define SBSTRIDE 36                   // bytes per sign row (32 batches + 4 pad)
// grid = OUT_ * (BATCH_/BPB) = 512 blocks, 256 threads

__global__ __launch_bounds__(256) void linlut_kernel(
    const float* __restrict__ x, const float* __restrict__ w,
    const float* __restrict__ bias, const float* __restrict__ means,
    const int* __restrict__ mask, float* __restrict__ out)
{
    __shared__ float         lut[128 * 33];          // lut[i*33 + lvl*16 + S]
    __shared__ unsigned char sbT[IN_ * SBSTRIDE];    // sbT[pos*36 + batch]: s0 | s1<<1
    __shared__ uint32_t      pidx[128];              // 4 gather indices per i, byte-packed
    __shared__ float         partial[8 * 33];        // partial[part*33 + batch]

    const int tid = threadIdx.x;
    const int o  = blockIdx.x >> 2;
    const int b0 = (blockIdx.x & 3) * BPB;

    const float m0 = fabsf(means[0]);
    const float m1 = fabsf(means[1]);
    const float bo = bias[o];

    // ---- stage 1: pack gather indices for this o ----
    if (tid < 128) {
        const int4 mm = *(const int4*)(mask + ((size_t)(o * IN_ + tid)) * 4);
        pidx[tid] = (uint32_t)mm.x | ((uint32_t)mm.y << 8) |
                    ((uint32_t)mm.z << 16) | ((uint32_t)mm.w << 24);
    }

    // ---- stage 2: sign bytes, transposed layout sbT[pos][batch] ----
    #pragma unroll
    for (int r = 0; r < 4; ++r) {
        const int item = tid + 256 * r;      // 0..1023
        const int b    = item >> 5;          // 0..31 local batch
        const int g    = item & 31;          // group of 4 consecutive pos
        const float4 xv = *(const float4*)(x + (size_t)(b0 + b) * IN_ + g * 4);
        const float vv[4] = {xv.x, xv.y, xv.z, xv.w};
        #pragma unroll
        for (int k = 0; k < 4; ++k) {
            const uint32_t s0 = (vv[k] >= 0.0f) ? 1u : 0u;
            const float rr = vv[k] - (s0 ? m0 : -m0);   // same f32 ops as reference
            const uint32_t s1 = (rr >= 0.0f) ? 1u : 0u;
            sbT[(4 * g + k) * SBSTRIDE + b] = (unsigned char)(s0 | (s1 << 1));
        }
    }

    // ---- stage 3: LUT slice for this o: lut[i*33 + lvl*16 + S] ----
    {
        const int i   = tid >> 1;        // 0..127
        const int lvl = tid & 1;
        const float m = lvl ? m1 : m0;
        const float p = (1.0f + m) * 0.5f;
        const float q = (1.0f - m) * 0.5f;
        float pw[5];
        pw[0] = p * p * p * p;
        pw[1] = p * p * p * q;
        pw[2] = p * p * q * q;
        pw[3] = p * q * q * q;
        pw[4] = q * q * q * q;
        const float* wr = w + ((size_t)(o * IN_ + i)) * KK_;
        float wv[16];
        #pragma unroll
        for (int c4 = 0; c4 < 4; ++c4) {
            const float4 t = *(const float4*)(wr + 4 * c4);
            wv[4 * c4 + 0] = t.x; wv[4 * c4 + 1] = t.y;
            wv[4 * c4 + 2] = t.z; wv[4 * c4 + 3] = t.w;
        }
        float* lr = lut + i * 33 + lvl * 16;
        #pragma unroll
        for (int S = 0; S < 16; ++S) {
            float acc = 0.0f;
            #pragma unroll
            for (int c = 0; c < 16; ++c)
                acc += wv[c] * pw[__popc(S ^ c)];   // popc folds at compile time
            lr[S] = acc;
        }
    }
    __syncthreads();

    // ---- stage 4: 32 lanes share one i (conflict-free gathers + LUT reads) ----
    const int bcol = tid & 31;           // local batch
    const int part = tid >> 5;           // 0..7 : i-partition
    const unsigned char* sb = sbT + bcol;
    float acc = 0.0f;
    #pragma unroll
    for (int j = 0; j < 16; ++j) {
        const int i = part * 16 + j;
        const uint32_t pk = pidx[i];                 // broadcast (same addr for 32 lanes)
        const uint32_t c0 = sb[(pk & 255u) * SBSTRIDE];
        const uint32_t c1 = sb[((pk >> 8) & 255u) * SBSTRIDE];
        const uint32_t c2 = sb[((pk >> 16) & 255u) * SBSTRIDE];
        const uint32_t c3 = sb[(pk >> 24) * SBSTRIDE];
        const uint32_t S0 = (c0 & 1u) | ((c1 & 1u) << 1) | ((c2 & 1u) << 2) | ((c3 & 1u) << 3);
        const uint32_t S1 = (c0 >> 1) | ((c1 >> 1) << 1) | ((c2 >> 1) << 2) | ((c3 >> 1) << 3);
        const float* lr = lut + i * 33;              // 16 consecutive words: 16 banks
        acc += lr[S0];
        acc += lr[16 + S1];
    }
    partial[part * 33 + bcol] = acc;
    __syncthreads();

    // ---- stage 5: reduce 8 parts per batch, store ----
    if (tid < 32) {
        float s = 0.0f;
        #pragma unroll
        for (int p = 0; p < 8; ++p)
            s += partial[p * 33 + tid];
        out[(size_t)(b0 + tid) * OUT_ + o] = s + bo;
    }
}

extern "C" void kernel_launch(void* const* d_in, const int* in_sizes, int n_in,
                              void* d_out, int out_size, void* d_ws, size_t ws_size,
                              hipStream_t stream) {
    const float* x     = (const float*)d_in[0];
    const float* w     = (const float*)d_in[1];
    const float* bias  = (const float*)d_in[2];
    const float* means = (const float*)d_in[3];
    const int*   mask  = (const int*)d_in[4];
    float* out = (float*)d_out;
    hipLaunchKernelGGL(linlut_kernel, dim3(512), dim3(256), 0, stream,
                       x, w, bias, means, mask, out);
}